// Round 6
// baseline (85.414 us; speedup 1.0000x reference)
//
#include <hip/hip_runtime.h>

#define NN 2048
#define KK 8
#define BB 32
#define TT 20
#define NT 512            // threads per block
#define OPT (NN / NT)     // 4 oscillators per thread

__global__ __launch_bounds__(NT) void osci_kernel(
    const float* __restrict__ coupling,   // [B,N,K]
    const float* __restrict__ phase0,     // [B,N]
    const float* __restrict__ omega,      // [B,N]
    const int*   __restrict__ conn,       // [N,K]
    float*       __restrict__ out)        // [T+1,B,N]
{
    const int b   = blockIdx.x;
    const int tid = threadIdx.x;

    // double-buffered phase table: buf0 = ph_tab[0..NN), buf1 = ph_tab[NN..2NN)
    // (buf1 accesses fold to ds_read/ds_write offset:8192 immediates)
    __shared__ float ph_tab[2 * NN];      // 16 KiB

    // per-thread state: OPT=4 oscillators (i = tid + t*NT)
    int   cidx[OPT][KK];
    float w[OPT][KK];
    float inv_n[OPT];
    float om[OPT];
    float ph[OPT];

    for (int t = 0; t < OPT; ++t) {
        const int i = tid + t * NT;
        float p = phase0[b * NN + i];
        ph[t] = p;
        ph_tab[i] = p;
        out[(size_t)b * NN + i] = p;      // out[0, b, i] = phase0
        om[t] = omega[b * NN + i];

        // vectorized setup loads (rows are 32B-aligned)
        const int4*   c4 = (const int4*)  &conn[i * KK];
        const float4* w4 = (const float4*)&coupling[((size_t)b * NN + i) * KK];
        int4   ja = c4[0], jb = c4[1];
        float4 va = w4[0], vb = w4[1];
        int   jj[KK] = { ja.x, ja.y, ja.z, ja.w, jb.x, jb.y, jb.z, jb.w };
        float vv[KK] = { va.x, va.y, va.z, va.w, vb.x, vb.y, vb.z, vb.w };

        // last-wins scatter dedup: entry k vanishes if any k2>k hits same column;
        // n = count of surviving nonzero dense-row entries
        int cnt = 0;
        #pragma unroll
        for (int k = 0; k < KK; ++k) {
            bool over = false;
            #pragma unroll
            for (int k2 = k + 1; k2 < KK; ++k2) over = over || (jj[k2] == jj[k]);
            if (over) vv[k] = 0.0f;
            if (vv[k] != 0.0f) ++cnt;
        }
        #pragma unroll
        for (int k = 0; k < KK; ++k) { cidx[t][k] = jj[k]; w[t][k] = vv[k]; }
        inv_n[t] = 1.0f / (float)cnt;     // cnt >= 1 always (last write survives)
    }
    __syncthreads();   // setup: full drain once is fine

    float* outp = out + ((size_t)BB + b) * NN;   // &out[1][b][0]

    #pragma unroll 1
    for (int sp = 0; sp < TT; sp += 2) {
        // ---- even step: read buf0, write buf1 ----
        {
            // issue all 32 gathers first (max MLP per wave), then compute
            float pj[OPT][KK];
            #pragma unroll
            for (int t = 0; t < OPT; ++t)
                #pragma unroll
                for (int k = 0; k < KK; ++k)
                    pj[t][k] = ph_tab[cidx[t][k]];          // ds_read offset:0

            #pragma unroll
            for (int t = 0; t < OPT; ++t) {
                const int i = tid + t * NT;
                float acc = 0.0f;
                #pragma unroll
                for (int k = 0; k < KK; ++k)
                    acc += w[t][k] * __sinf(pj[t][k] - ph[t]);  // bit-identical math
                const float pn = ph[t] + acc * inv_n[t] + om[t]; // eps=1, ANNEAL=0
                ph[t] = pn;
                ph_tab[NN + i] = pn;                        // ds_write offset:8192
                outp[i] = pn;                               // fire-and-forget HBM store
            }
        }
        // LDS-only barrier: own ds_reads (WAR) + ds_writes (RAW) complete; no vmcnt drain
        asm volatile("s_waitcnt lgkmcnt(0)" ::: "memory");
        __builtin_amdgcn_s_barrier();
        asm volatile("" ::: "memory");
        outp += (size_t)BB * NN;

        // ---- odd step: read buf1, write buf0 ----
        {
            float pj[OPT][KK];
            #pragma unroll
            for (int t = 0; t < OPT; ++t)
                #pragma unroll
                for (int k = 0; k < KK; ++k)
                    pj[t][k] = ph_tab[NN + cidx[t][k]];     // ds_read offset:8192

            #pragma unroll
            for (int t = 0; t < OPT; ++t) {
                const int i = tid + t * NT;
                float acc = 0.0f;
                #pragma unroll
                for (int k = 0; k < KK; ++k)
                    acc += w[t][k] * __sinf(pj[t][k] - ph[t]);
                const float pn = ph[t] + acc * inv_n[t] + om[t];
                ph[t] = pn;
                ph_tab[i] = pn;                             // ds_write offset:0
                outp[i] = pn;
            }
        }
        asm volatile("s_waitcnt lgkmcnt(0)" ::: "memory");
        __builtin_amdgcn_s_barrier();
        asm volatile("" ::: "memory");
        outp += (size_t)BB * NN;
    }
}

extern "C" void kernel_launch(void* const* d_in, const int* in_sizes, int n_in,
                              void* d_out, int out_size, void* d_ws, size_t ws_size,
                              hipStream_t stream) {
    const float* coupling = (const float*)d_in[0];   // [B,N,K]
    const float* phase0   = (const float*)d_in[1];   // [B,N]
    const float* omega    = (const float*)d_in[2];   // [B,N]
    const int*   conn     = (const int*)d_in[3];     // [N,K]
    float* out = (float*)d_out;                      // [T+1,B,N]

    osci_kernel<<<BB, NT, 0, stream>>>(coupling, phase0, omega, conn, out);
}

// Round 7
// 81.154 us; speedup vs baseline: 1.0525x; 1.0525x over previous
//
#include <hip/hip_runtime.h>

#define NN 2048
#define KK 8
#define BB 32
#define TT 20

// LDS layout (float2 elements):
//   [0,2048)      even buffer, copy 0     (lanes 0-31 gather here)
//   [2048,4096)   even buffer, copy 1     (lanes 32-63 gather here)
//   [4096,6144)   odd  buffer, copy 0
//   [6144,8192)   odd  buffer, copy 1
// Odd-buffer accesses are the same registers + element offset 4096
// (= byte offset 32768, folds into the ds_read/ds_write 16-bit immediate).
__global__ __launch_bounds__(1024) void osci_kernel(
    const float* __restrict__ coupling,   // [B,N,K]
    const float* __restrict__ phase0,     // [B,N]
    const float* __restrict__ omega,      // [B,N]
    const int*   __restrict__ conn,       // [N,K]
    float*       __restrict__ out)        // [T+1,B,N]
{
    const int b   = blockIdx.x;
    const int tid = threadIdx.x;
    const int half = (tid & 32) ? 2048 : 0;   // which table copy this lane gathers

    __shared__ float2 sc_tab[8 * NN / 2];     // 8192 float2 = 64 KiB

    // per-thread state: 2 oscillators (i = tid, tid+1024)
    int   gidx[2][KK];                        // gather element index incl. copy select
    float w[2][KK];
    float inv_n[2];
    float om[2];
    float ph[2];
    float si[2], ci[2];

    for (int t = 0; t < 2; ++t) {
        const int i = tid + t * 1024;
        float p = phase0[b * NN + i];
        ph[t] = p;
        float s, c;
        __sincosf(p, &s, &c);
        si[t] = s; ci[t] = c;
        sc_tab[i]        = make_float2(s, c);   // even buf, copy 0
        sc_tab[2048 + i] = make_float2(s, c);   // even buf, copy 1
        out[(size_t)b * NN + i] = p;            // out[0, b, i] = phase0
        om[t] = omega[b * NN + i];

        // vectorized setup loads (rows are 32B-aligned)
        const int4*   c4 = (const int4*)  &conn[i * KK];
        const float4* w4 = (const float4*)&coupling[((size_t)b * NN + i) * KK];
        int4   ja = c4[0], jb = c4[1];
        float4 va = w4[0], vb = w4[1];
        int   jj[KK] = { ja.x, ja.y, ja.z, ja.w, jb.x, jb.y, jb.z, jb.w };
        float vv[KK] = { va.x, va.y, va.z, va.w, vb.x, vb.y, vb.z, vb.w };

        // last-wins scatter dedup: entry k vanishes if any k2>k hits same column;
        // n = count of surviving nonzero dense-row entries
        int cnt = 0;
        #pragma unroll
        for (int k = 0; k < KK; ++k) {
            bool over = false;
            #pragma unroll
            for (int k2 = k + 1; k2 < KK; ++k2) over = over || (jj[k2] == jj[k]);
            if (over) vv[k] = 0.0f;
            if (vv[k] != 0.0f) ++cnt;
        }
        #pragma unroll
        for (int k = 0; k < KK; ++k) { gidx[t][k] = jj[k] + half; w[t][k] = vv[k]; }
        inv_n[t] = 1.0f / (float)cnt;         // cnt >= 1 always (last write survives)
    }
    __syncthreads();   // setup: full drain once is fine

    float* outp = out + ((size_t)BB + b) * NN;   // &out[1][b][0]

    #pragma unroll 1
    for (int sp = 0; sp < TT; sp += 2) {
        // ================ even step: read even buf, write odd buf ================
        #pragma unroll
        for (int t = 0; t < 2; ++t) {
            const int i = tid + t * 1024;
            // Cs = Σ w·sin(φ_j), Cc = Σ w·cos(φ_j)   (reference decomposition)
            float cs = 0.0f, cc = 0.0f;
            #pragma unroll
            for (int k = 0; k < KK; ++k) {
                const float2 v = sc_tab[gidx[t][k]];          // ds_read_b64 offset:0
                cs += w[t][k] * v.x;
                cc += w[t][k] * v.y;
            }
            // delta = (Cs·c_i − Cc·s_i)/n   (eps=1, ANNEAL=0)
            const float pn = ph[t] + (cs * ci[t] - cc * si[t]) * inv_n[t] + om[t];
            ph[t] = pn;
            float sn, cn;
            __sincosf(pn, &sn, &cn);
            si[t] = sn; ci[t] = cn;
            const float2 scn = make_float2(sn, cn);
            sc_tab[4096 + i]        = scn;     // odd buf copy 0 (offset:32768)
            sc_tab[4096 + 2048 + i] = scn;     // odd buf copy 1 (offset:49152)
            outp[i] = pn;                      // fire-and-forget HBM store
        }
        // LDS-only barrier: own ds_reads (WAR) + ds_writes (RAW) complete; no vmcnt drain
        asm volatile("s_waitcnt lgkmcnt(0)" ::: "memory");
        __builtin_amdgcn_s_barrier();
        asm volatile("" ::: "memory");
        outp += (size_t)BB * NN;

        // ================ odd step: read odd buf, write even buf ================
        #pragma unroll
        for (int t = 0; t < 2; ++t) {
            const int i = tid + t * 1024;
            float cs = 0.0f, cc = 0.0f;
            #pragma unroll
            for (int k = 0; k < KK; ++k) {
                const float2 v = sc_tab[4096 + gidx[t][k]];   // ds_read_b64 offset:32768
                cs += w[t][k] * v.x;
                cc += w[t][k] * v.y;
            }
            const float pn = ph[t] + (cs * ci[t] - cc * si[t]) * inv_n[t] + om[t];
            ph[t] = pn;
            float sn, cn;
            __sincosf(pn, &sn, &cn);
            si[t] = sn; ci[t] = cn;
            const float2 scn = make_float2(sn, cn);
            sc_tab[i]        = scn;            // even buf copy 0 (offset:0)
            sc_tab[2048 + i] = scn;            // even buf copy 1 (offset:16384)
            outp[i] = pn;
        }
        asm volatile("s_waitcnt lgkmcnt(0)" ::: "memory");
        __builtin_amdgcn_s_barrier();
        asm volatile("" ::: "memory");
        outp += (size_t)BB * NN;
    }
}

extern "C" void kernel_launch(void* const* d_in, const int* in_sizes, int n_in,
                              void* d_out, int out_size, void* d_ws, size_t ws_size,
                              hipStream_t stream) {
    const float* coupling = (const float*)d_in[0];   // [B,N,K]
    const float* phase0   = (const float*)d_in[1];   // [B,N]
    const float* omega    = (const float*)d_in[2];   // [B,N]
    const int*   conn     = (const int*)d_in[3];     // [N,K]
    float* out = (float*)d_out;                      // [T+1,B,N]

    osci_kernel<<<BB, 1024, 0, stream>>>(coupling, phase0, omega, conn, out);
}

// Round 8
// 79.990 us; speedup vs baseline: 1.0678x; 1.0146x over previous
//
#include <hip/hip_runtime.h>

#define NN 2048
#define KK 8
#define BB 32
#define TT 20

// Best measured variant (session R4, 79.62 us): 1024 thr x 2 osc, (sin,cos)
// LDS table double-buffered, LDS-only (lgkmcnt) step barrier, fire-and-forget
// HBM output stores. Five structural variants (pipe remixes, replication,
// 512x4) all land 79.6-85.4 us => phase-lockstep latency floor, not pipe-bound.
__global__ __launch_bounds__(1024) void osci_kernel(
    const float* __restrict__ coupling,   // [B,N,K]
    const float* __restrict__ phase0,     // [B,N]
    const float* __restrict__ omega,      // [B,N]
    const int*   __restrict__ conn,       // [N,K]
    float*       __restrict__ out)        // [T+1,B,N]
{
    const int b   = blockIdx.x;
    const int tid = threadIdx.x;

    // double-buffered (sin,cos) table: buf0 = sc_buf[0..NN), buf1 = sc_buf[NN..2NN)
    // buf1 accesses fold to ds_read_b64/ds_write_b64 offset:16384 immediates
    __shared__ float2 sc_buf[2 * NN];     // 32 KiB

    // per-thread state: 2 oscillators each (2*1024 = 2048)
    int   cidx[2][KK];
    float w[2][KK];
    float inv_n[2];
    float om[2];
    float ph[2];
    float si[2], ci[2];

    for (int t = 0; t < 2; ++t) {
        const int i = tid + t * 1024;
        float p = phase0[b * NN + i];
        ph[t] = p;
        float s, c;
        __sincosf(p, &s, &c);
        si[t] = s; ci[t] = c;
        sc_buf[i] = make_float2(s, c);
        out[(size_t)b * NN + i] = p;          // out[0, b, i] = phase0
        om[t] = omega[b * NN + i];

        // vectorized setup loads (rows are 32B-aligned)
        const int4*   c4 = (const int4*)  &conn[i * KK];
        const float4* w4 = (const float4*)&coupling[((size_t)b * NN + i) * KK];
        int4   ja = c4[0], jb = c4[1];
        float4 va = w4[0], vb = w4[1];
        int   jj[KK] = { ja.x, ja.y, ja.z, ja.w, jb.x, jb.y, jb.z, jb.w };
        float vv[KK] = { va.x, va.y, va.z, va.w, vb.x, vb.y, vb.z, vb.w };

        // last-wins scatter dedup: entry k vanishes if any k2>k hits same column;
        // n = count of surviving nonzero dense-row entries
        int cnt = 0;
        #pragma unroll
        for (int k = 0; k < KK; ++k) {
            bool over = false;
            #pragma unroll
            for (int k2 = k + 1; k2 < KK; ++k2) over = over || (jj[k2] == jj[k]);
            if (over) vv[k] = 0.0f;
            if (vv[k] != 0.0f) ++cnt;
        }
        #pragma unroll
        for (int k = 0; k < KK; ++k) { cidx[t][k] = jj[k]; w[t][k] = vv[k]; }
        inv_n[t] = 1.0f / (float)cnt;         // cnt >= 1 always (last write survives)
    }
    __syncthreads();   // setup: full drain once is fine

    float* outp = out + ((size_t)BB + b) * NN;   // &out[1][b][0]

    #pragma unroll 1
    for (int sp = 0; sp < TT; sp += 2) {
        // ---- even step: read buf0, write buf1 ----
        #pragma unroll
        for (int t = 0; t < 2; ++t) {
            const int i = tid + t * 1024;
            // reference decomposition: Cs = Σ w·sin(φ_j), Cc = Σ w·cos(φ_j)
            float cs = 0.0f, cc = 0.0f;
            #pragma unroll
            for (int k = 0; k < KK; ++k) {
                const float2 v = sc_buf[cidx[t][k]];        // ds_read_b64 offset:0
                cs += w[t][k] * v.x;
                cc += w[t][k] * v.y;
            }
            // delta = (Cs·c_i − Cc·s_i)/n   (eps=1, ANNEAL=0)
            const float pn = ph[t] + (cs * ci[t] - cc * si[t]) * inv_n[t] + om[t];
            ph[t] = pn;
            float sn, cn;
            __sincosf(pn, &sn, &cn);
            si[t] = sn; ci[t] = cn;
            sc_buf[NN + i] = make_float2(sn, cn);           // ds_write_b64 offset:16384
            outp[i] = pn;                                   // fire-and-forget HBM store
        }
        // LDS-only barrier: own ds_reads (WAR) + ds_writes (RAW) complete; no vmcnt drain
        asm volatile("s_waitcnt lgkmcnt(0)" ::: "memory");
        __builtin_amdgcn_s_barrier();
        asm volatile("" ::: "memory");
        outp += (size_t)BB * NN;

        // ---- odd step: read buf1, write buf0 ----
        #pragma unroll
        for (int t = 0; t < 2; ++t) {
            const int i = tid + t * 1024;
            float cs = 0.0f, cc = 0.0f;
            #pragma unroll
            for (int k = 0; k < KK; ++k) {
                const float2 v = sc_buf[NN + cidx[t][k]];   // ds_read_b64 offset:16384
                cs += w[t][k] * v.x;
                cc += w[t][k] * v.y;
            }
            const float pn = ph[t] + (cs * ci[t] - cc * si[t]) * inv_n[t] + om[t];
            ph[t] = pn;
            float sn, cn;
            __sincosf(pn, &sn, &cn);
            si[t] = sn; ci[t] = cn;
            sc_buf[i] = make_float2(sn, cn);                // ds_write_b64 offset:0
            outp[i] = pn;
        }
        asm volatile("s_waitcnt lgkmcnt(0)" ::: "memory");
        __builtin_amdgcn_s_barrier();
        asm volatile("" ::: "memory");
        outp += (size_t)BB * NN;
    }
}

extern "C" void kernel_launch(void* const* d_in, const int* in_sizes, int n_in,
                              void* d_out, int out_size, void* d_ws, size_t ws_size,
                              hipStream_t stream) {
    const float* coupling = (const float*)d_in[0];   // [B,N,K]
    const float* phase0   = (const float*)d_in[1];   // [B,N]
    const float* omega    = (const float*)d_in[2];   // [B,N]
    const int*   conn     = (const int*)d_in[3];     // [N,K]
    float* out = (float*)d_out;                      // [T+1,B,N]

    osci_kernel<<<BB, 1024, 0, stream>>>(coupling, phase0, omega, conn, out);
}